// Round 2
// baseline (1285.523 us; speedup 1.0000x reference)
//
#include <hip/hip_runtime.h>
#include <hip/hip_bf16.h>
#include <math.h>

#define N_GENE 50000
#define N_DIS  25000
#define F_GENE 512
#define F_DIS  256
#define E_EDGES 150000
#define BN_EPS 1e-5f

typedef unsigned short u16;

__device__ __forceinline__ u16 f2bf(float f) {
    union { float f; unsigned u; } c; c.f = f;
    unsigned u = c.u;
    unsigned rounding = 0x7FFFu + ((u >> 16) & 1u);
    return (u16)((u + rounding) >> 16);
}
__device__ __forceinline__ void load_bf16x8(const u16* p, float* f) {
    uint4 q = *reinterpret_cast<const uint4*>(p);
    unsigned w0 = q.x, w1 = q.y, w2 = q.z, w3 = q.w;
    f[0] = __uint_as_float(w0 << 16); f[1] = __uint_as_float(w0 & 0xffff0000u);
    f[2] = __uint_as_float(w1 << 16); f[3] = __uint_as_float(w1 & 0xffff0000u);
    f[4] = __uint_as_float(w2 << 16); f[5] = __uint_as_float(w2 & 0xffff0000u);
    f[6] = __uint_as_float(w3 << 16); f[7] = __uint_as_float(w3 & 0xffff0000u);
}

// ---------------- zero fill ----------------
__global__ void zero_kernel(int* p, int n) {
    int i = blockIdx.x * 256 + threadIdx.x;
    if (i < n) p[i] = 0;
}

// ---- encoder GEMM: out = relu(A[M,K]f32 @ W[K,128]f32 + b) -> f32 ----
template <int K>
__global__ void encode_gemm(const float* __restrict__ A, const float* __restrict__ W,
                            const float* __restrict__ bias, float* __restrict__ out, int M) {
    __shared__ float As[4][K];
    int block_row = blockIdx.x * 4;
    int tid = threadIdx.x;  // 128 threads
    for (int idx = tid; idx < 4 * K; idx += 128) {
        int r = idx / K, k = idx % K;
        As[r][k] = A[(size_t)(block_row + r) * K + k];
    }
    __syncthreads();
    int col = tid;
    float a0 = 0.f, a1 = 0.f, a2 = 0.f, a3 = 0.f;
    for (int k = 0; k < K; k++) {
        float w = W[k * 128 + col];
        a0 += As[0][k] * w; a1 += As[1][k] * w;
        a2 += As[2][k] * w; a3 += As[3][k] * w;
    }
    float b = bias[col];
    out[(size_t)(block_row + 0) * 128 + col] = fmaxf(a0 + b, 0.f);
    out[(size_t)(block_row + 1) * 128 + col] = fmaxf(a1 + b, 0.f);
    out[(size_t)(block_row + 2) * 128 + col] = fmaxf(a2 + b, 0.f);
    out[(size_t)(block_row + 3) * 128 + col] = fmaxf(a3 + b, 0.f);
}

// ---- batchnorm stats (col sums + sumsq into stats[0..127],[128..255]) ----
__global__ void col_stats(const float* __restrict__ X, int M, float* __restrict__ stats) {
    int col = threadIdx.x;  // 128
    float s = 0.f, s2 = 0.f;
    for (int r = blockIdx.x; r < M; r += gridDim.x) {
        float v = X[(size_t)r * 128 + col];
        s += v; s2 += v * v;
    }
    atomicAdd(&stats[col], s);
    atomicAdd(&stats[128 + col], s2);
}

__global__ void bn_apply(float* __restrict__ X, const float* __restrict__ stats,
                         const float* __restrict__ gamma, const float* __restrict__ beta, int M) {
    int i = blockIdx.x * 256 + threadIdx.x;
    if (i >= M * 128) return;
    int col = i & 127;
    float inv_m = 1.0f / (float)M;
    float mu = stats[col] * inv_m;
    float var = stats[128 + col] * inv_m - mu * mu;
    float g = gamma[col], b = beta[col];
    X[i] = g * (X[i] - mu) * rsqrtf(var + BN_EPS) + b;
}

// ---- feature GEMM: xs = A[M,128]f32 @ W[128,512]f32 -> bf16 ----
__global__ void feat_gemm(const float* __restrict__ A, const float* __restrict__ W,
                          u16* __restrict__ out, int M) {
    __shared__ float As[2][128];
    int row0 = blockIdx.x * 2;
    int tid = threadIdx.x;  // 512
    if (tid < 256) {
        int r = tid >> 7, k = tid & 127;
        As[r][k] = A[(size_t)(row0 + r) * 128 + k];
    }
    __syncthreads();
    int col = tid;
    float a0 = 0.f, a1 = 0.f;
    for (int k = 0; k < 128; k++) {
        float w = W[k * 512 + col];
        a0 += As[0][k] * w; a1 += As[1][k] * w;
    }
    out[(size_t)(row0 + 0) * 512 + col] = f2bf(a0);
    out[(size_t)(row0 + 1) * 512 + col] = f2bf(a1);
}

// ---- weff[h*128+k] = sum_c Wd[k, h*128+c] * ad[h*128+c] ----
__global__ void weff_kernel(const float* __restrict__ Wd, const float* __restrict__ ad,
                            float* __restrict__ weff) {
    int t = blockIdx.x * 256 + threadIdx.x;
    if (t >= 512) return;
    int h = t >> 7, k = t & 127;
    float s = 0.f;
    for (int c = 0; c < 128; c++)
        s += Wd[k * 512 + h * 128 + c] * ad[h * 128 + c];
    weff[h * 128 + k] = s;
}

// ---- ld[n,h] = X[n,:] @ weff[h,:]  (one wave per node) ----
__global__ void ld_kernel(const float* __restrict__ X, const float* __restrict__ weff,
                          float* __restrict__ ld, int M) {
    int wid = (blockIdx.x * blockDim.x + threadIdx.x) >> 6;
    int lane = threadIdx.x & 63;
    if (wid >= M) return;
    float x0 = X[(size_t)wid * 128 + lane];
    float x1 = X[(size_t)wid * 128 + 64 + lane];
    #pragma unroll
    for (int h = 0; h < 4; h++) {
        float p = x0 * weff[h * 128 + lane] + x1 * weff[h * 128 + 64 + lane];
        p += __shfl_xor(p, 32, 64);
        p += __shfl_xor(p, 16, 64);
        p += __shfl_xor(p, 8, 64);
        p += __shfl_xor(p, 4, 64);
        p += __shfl_xor(p, 2, 64);
        p += __shfl_xor(p, 1, 64);
        if (lane == 0) ld[wid * 4 + h] = p;
    }
}

// ---- ls[n,h] = sum_c xs[n,h,c]*as[h,c]  (one wave per node; xs bf16, as f32) ----
__global__ void ls_kernel(const u16* __restrict__ xs, const float* __restrict__ as_,
                          float* __restrict__ ls, int M) {
    int wid = (blockIdx.x * blockDim.x + threadIdx.x) >> 6;
    int lane = threadIdx.x & 63;
    if (wid >= M) return;
    float xv[8];
    load_bf16x8(xs + (size_t)wid * 512 + lane * 8, xv);
    const float* ap = as_ + lane * 8;
    float s = 0.f;
    #pragma unroll
    for (int k = 0; k < 8; k++) s += xv[k] * ap[k];
    s += __shfl_xor(s, 1, 64);
    s += __shfl_xor(s, 2, 64);
    s += __shfl_xor(s, 4, 64);
    s += __shfl_xor(s, 8, 64);
    if ((lane & 15) == 0) ls[wid * 4 + (lane >> 4)] = s;
}

// ---------------- CSR build ----------------
__global__ void count_edges(const int* __restrict__ src, const int* __restrict__ dst,
                            int E, int n_loop, int* __restrict__ deg) {
    int e = blockIdx.x * 256 + threadIdx.x;
    if (e >= E + n_loop) return;
    int s, d;
    if (e < E) { s = src[e]; d = dst[e]; if (s == d) return; }
    else { s = e - E; d = s; }
    atomicAdd(&deg[d], 1);
}

__global__ void scan_kernel(const int* __restrict__ deg, int* __restrict__ offs,
                            int* __restrict__ cursor, int n) {
    __shared__ int sums[1024];
    int tid = threadIdx.x;
    int per = (n + 1023) / 1024;
    int start = tid * per;
    int local = 0;
    for (int i = 0; i < per; i++) {
        int idx = start + i;
        if (idx < n) local += deg[idx];
    }
    sums[tid] = local;
    __syncthreads();
    for (int off = 1; off < 1024; off <<= 1) {
        int v = (tid >= off) ? sums[tid - off] : 0;
        __syncthreads();
        sums[tid] += v;
        __syncthreads();
    }
    int run = (tid == 0) ? 0 : sums[tid - 1];
    for (int i = 0; i < per; i++) {
        int idx = start + i;
        if (idx < n) { offs[idx] = run; cursor[idx] = run; run += deg[idx]; }
    }
    if (tid == 1023) offs[n] = sums[1023];
}

__global__ void scatter_edges(const int* __restrict__ src, const int* __restrict__ dst,
                              int E, int n_loop, int* __restrict__ cursor,
                              int* __restrict__ esrc) {
    int e = blockIdx.x * 256 + threadIdx.x;
    if (e >= E + n_loop) return;
    int s, d;
    if (e < E) { s = src[e]; d = dst[e]; if (s == d) return; }
    else { s = e - E; d = s; }
    int pos = atomicAdd(&cursor[d], 1);
    esrc[pos] = s;
}

// ---- GAT aggregation: one wave per dst node; updates xdst_out in place ----
__global__ void gat_kernel(const int* __restrict__ offs, const int* __restrict__ esrc,
                           const float* __restrict__ ls, const float* __restrict__ ld,
                           const u16* __restrict__ xs, const float* __restrict__ bias,
                           float* __restrict__ xdst_out, int n_dst) {
    int wid = (blockIdx.x * blockDim.x + threadIdx.x) >> 6;
    int lane = threadIdx.x & 63;
    if (wid >= n_dst) return;
    int h = lane >> 4;
    int beg = offs[wid], end = offs[wid + 1];
    float ldv = ld[wid * 4 + h];
    float m = -INFINITY;
    for (int j = beg; j < end; j++) {
        int s = esrc[j];
        float l = ls[s * 4 + h] + ldv;
        l = l > 0.f ? l : 0.2f * l;
        m = fmaxf(m, l);
    }
    float denom = 0.f;
    float acc[8] = {0.f, 0.f, 0.f, 0.f, 0.f, 0.f, 0.f, 0.f};
    for (int j = beg; j < end; j++) {
        int s = esrc[j];
        float l = ls[s * 4 + h] + ldv;
        l = l > 0.f ? l : 0.2f * l;
        float p = __expf(l - m);
        denom += p;
        float xv[8];
        load_bf16x8(xs + (size_t)s * 512 + lane * 8, xv);
        #pragma unroll
        for (int k = 0; k < 8; k++) acc[k] += p * xv[k];
    }
    float dinv = denom > 0.f ? 1.f / denom : 1.f;
    #pragma unroll
    for (int k = 0; k < 8; k++) {
        float v = acc[k] * dinv;
        v += __shfl_xor(v, 16, 64);
        v += __shfl_xor(v, 32, 64);
        acc[k] = v * 0.25f;
    }
    if (lane < 16) {
        int c0 = lane * 8;
        #pragma unroll
        for (int k = 0; k < 8; k++) {
            xdst_out[(size_t)wid * 128 + c0 + k] += acc[k] + bias[c0 + k];
        }
    }
}

// ---------------- final copy to f32 output ----------------
__global__ void copy_out(const float* __restrict__ gene, const float* __restrict__ dis,
                         float* __restrict__ out) {
    int i = blockIdx.x * 256 + threadIdx.x;
    const int NG = N_GENE * 128, ND = N_DIS * 128;
    if (i < NG) out[i] = gene[i];
    else if (i < NG + ND) out[i] = dis[i - NG];
}

static inline int cdiv(int a, int b) { return (a + b - 1) / b; }

extern "C" void kernel_launch(void* const* d_in, const int* in_sizes, int n_in,
                              void* d_out, int out_size, void* d_ws, size_t ws_size,
                              hipStream_t stream) {
    const float* x_gene = (const float*)d_in[0];
    const float* x_dis  = (const float*)d_in[1];
    const int* e1s = (const int*)d_in[2];
    const int* e1d = (const int*)d_in[3];
    const int* e2s = (const int*)d_in[4];
    const int* e2d = (const int*)d_in[5];
    const float *Wg = (const float*)d_in[6],  *bg = (const float*)d_in[7];
    const float *gg = (const float*)d_in[8],  *betag = (const float*)d_in[9];
    const float *Wd = (const float*)d_in[10], *bd = (const float*)d_in[11];
    const float *gd = (const float*)d_in[12], *betad = (const float*)d_in[13];
    const float *W1s = (const float*)d_in[14], *W1d = (const float*)d_in[15];
    const float *a1s = (const float*)d_in[16], *a1d = (const float*)d_in[17];
    const float *b1  = (const float*)d_in[18];
    const float *W2s = (const float*)d_in[19], *W2d = (const float*)d_in[20];
    const float *a2s = (const float*)d_in[21], *a2d = (const float*)d_in[22];
    const float *b2  = (const float*)d_in[23];

    // workspace layout (all 256B aligned)
    char* p = (char*)d_ws;
    auto alloc = [&](size_t bytes) {
        char* r = p;
        p += (bytes + 255) & ~(size_t)255;
        return r;
    };
    float* gene_f = (float*)alloc((size_t)N_GENE * 128 * 4);
    float* dis_f  = (float*)alloc((size_t)N_DIS * 128 * 4);
    u16*   xs_buf = (u16*)  alloc((size_t)N_GENE * 512 * 2);
    float* ls_buf = (float*)alloc((size_t)N_GENE * 4 * 4);
    float* ld_buf = (float*)alloc((size_t)N_GENE * 4 * 4);
    float* weff   = (float*)alloc(512 * 4);
    float* stats  = (float*)alloc(256 * 4);
    int*   deg    = (int*)  alloc((size_t)N_GENE * 4);
    int*   offs   = (int*)  alloc((size_t)(N_GENE + 1) * 4);
    int*   cursor = (int*)  alloc((size_t)N_GENE * 4);
    int*   esrc   = (int*)  alloc((size_t)(E_EDGES + N_GENE) * 4);

    // ---- encode gene: relu(x_gene @ Wg + bg) -> BN ----
    zero_kernel<<<1, 256, 0, stream>>>((int*)stats, 256);
    encode_gemm<512><<<N_GENE / 4, 128, 0, stream>>>(x_gene, Wg, bg, gene_f, N_GENE);
    col_stats<<<512, 128, 0, stream>>>(gene_f, N_GENE, stats);
    bn_apply<<<cdiv(N_GENE * 128, 256), 256, 0, stream>>>(gene_f, stats, gg, betag, N_GENE);

    // ---- encode dis ----
    zero_kernel<<<1, 256, 0, stream>>>((int*)stats, 256);
    encode_gemm<256><<<N_DIS / 4, 128, 0, stream>>>(x_dis, Wd, bd, dis_f, N_DIS);
    col_stats<<<512, 128, 0, stream>>>(dis_f, N_DIS, stats);
    bn_apply<<<cdiv(N_DIS * 128, 256), 256, 0, stream>>>(dis_f, stats, gd, betad, N_DIS);

    // ---- relation 1: Disease -> Gene ----
    feat_gemm<<<N_DIS / 2, 512, 0, stream>>>(dis_f, W1s, xs_buf, N_DIS);
    ls_kernel<<<cdiv(N_DIS, 4), 256, 0, stream>>>(xs_buf, a1s, ls_buf, N_DIS);
    weff_kernel<<<2, 256, 0, stream>>>(W1d, a1d, weff);
    ld_kernel<<<cdiv(N_GENE, 4), 256, 0, stream>>>(gene_f, weff, ld_buf, N_GENE);
    zero_kernel<<<cdiv(N_GENE, 256), 256, 0, stream>>>(deg, N_GENE);
    count_edges<<<cdiv(E_EDGES + N_DIS, 256), 256, 0, stream>>>(e1s, e1d, E_EDGES, N_DIS, deg);
    scan_kernel<<<1, 1024, 0, stream>>>(deg, offs, cursor, N_GENE);
    scatter_edges<<<cdiv(E_EDGES + N_DIS, 256), 256, 0, stream>>>(e1s, e1d, E_EDGES, N_DIS, cursor, esrc);
    gat_kernel<<<cdiv(N_GENE, 4), 256, 0, stream>>>(offs, esrc, ls_buf, ld_buf, xs_buf, b1, gene_f, N_GENE);

    // ---- relation 2: Gene -> Gene (updated gene) ----
    feat_gemm<<<N_GENE / 2, 512, 0, stream>>>(gene_f, W2s, xs_buf, N_GENE);
    ls_kernel<<<cdiv(N_GENE, 4), 256, 0, stream>>>(xs_buf, a2s, ls_buf, N_GENE);
    weff_kernel<<<2, 256, 0, stream>>>(W2d, a2d, weff);
    ld_kernel<<<cdiv(N_GENE, 4), 256, 0, stream>>>(gene_f, weff, ld_buf, N_GENE);
    zero_kernel<<<cdiv(N_GENE, 256), 256, 0, stream>>>(deg, N_GENE);
    count_edges<<<cdiv(E_EDGES + N_GENE, 256), 256, 0, stream>>>(e2s, e2d, E_EDGES, N_GENE, deg);
    scan_kernel<<<1, 1024, 0, stream>>>(deg, offs, cursor, N_GENE);
    scatter_edges<<<cdiv(E_EDGES + N_GENE, 256), 256, 0, stream>>>(e2s, e2d, E_EDGES, N_GENE, cursor, esrc);
    gat_kernel<<<cdiv(N_GENE, 4), 256, 0, stream>>>(offs, esrc, ls_buf, ld_buf, xs_buf, b2, gene_f, N_GENE);

    // ---- output ----
    copy_out<<<cdiv((N_GENE + N_DIS) * 128, 256), 256, 0, stream>>>(gene_f, dis_f, (float*)d_out);
}

// Round 3
// 958.028 us; speedup vs baseline: 1.3418x; 1.3418x over previous
//
#include <hip/hip_runtime.h>
#include <hip/hip_bf16.h>
#include <math.h>

#define N_GENE 50000
#define N_DIS  25000
#define F_GENE 512
#define F_DIS  256
#define E_EDGES 150000
#define BN_EPS 1e-5f

typedef unsigned short u16;
typedef short s16x8 __attribute__((ext_vector_type(8)));
typedef float f32x4 __attribute__((ext_vector_type(4)));

__device__ __forceinline__ u16 f2bf(float f) {
    union { float f; unsigned u; } c; c.f = f;
    unsigned u = c.u;
    unsigned rounding = 0x7FFFu + ((u >> 16) & 1u);
    return (u16)((u + rounding) >> 16);
}
__device__ __forceinline__ void load_bf16x8(const u16* p, float* f) {
    uint4 q = *reinterpret_cast<const uint4*>(p);
    unsigned w0 = q.x, w1 = q.y, w2 = q.z, w3 = q.w;
    f[0] = __uint_as_float(w0 << 16); f[1] = __uint_as_float(w0 & 0xffff0000u);
    f[2] = __uint_as_float(w1 << 16); f[3] = __uint_as_float(w1 & 0xffff0000u);
    f[4] = __uint_as_float(w2 << 16); f[5] = __uint_as_float(w2 & 0xffff0000u);
    f[6] = __uint_as_float(w3 << 16); f[7] = __uint_as_float(w3 & 0xffff0000u);
}

// ---------------- zero fill ----------------
__global__ void zero_kernel(int* p, int n) {
    int i = blockIdx.x * 256 + threadIdx.x;
    if (i < n) p[i] = 0;
}

// ---- W pre-transpose: wt[n*K+k] = bf16(W[k*N+n]) ----
__global__ void wtrans_kernel(const float* __restrict__ W, u16* __restrict__ wt, int K, int N) {
    int i = blockIdx.x * 256 + threadIdx.x;
    if (i >= K * N) return;
    int k = i / N, n = i - k * N;
    wt[n * K + k] = f2bf(W[i]);
}

// ---- MFMA GEMM: out[M,N] = op(A[M,K]f32 @ Wt^T) ; Wt is [N,K] bf16 ----
// one wave = 16 rows; A frags preloaded in VGPRs; N-tiles looped with 4-reg acc.
template <int K, int N, bool RELU_BIAS, bool OUT_BF16>
__global__ __launch_bounds__(256) void mfma_gemm(const float* __restrict__ A,
                                                 const u16* __restrict__ Wt,
                                                 const float* __restrict__ bias,
                                                 void* __restrict__ outp, int M) {
    constexpr int KC = K / 32;   // k-chunks of 32
    constexpr int NT = N / 16;   // n-tiles of 16
    int wave = threadIdx.x >> 6;
    int lane = threadIdx.x & 63;
    int m0 = (blockIdx.x * 4 + wave) * 16;
    if (m0 >= M) return;                 // wave-uniform
    int mrow = lane & 15;
    int quad = lane >> 4;
    int row = m0 + mrow;
    int arow = row < M ? row : M - 1;    // clamp OOB loads; stores guarded below

    // preload + convert A fragments: A[m=lane&15][k=quad*8+j] per chunk
    s16x8 afr[KC];
#pragma unroll
    for (int kc = 0; kc < KC; kc++) {
        const float* ap = A + (size_t)arow * K + kc * 32 + quad * 8;
        float4 lo = *reinterpret_cast<const float4*>(ap);
        float4 hi = *reinterpret_cast<const float4*>(ap + 4);
        s16x8 f;
        f[0] = (short)f2bf(lo.x); f[1] = (short)f2bf(lo.y);
        f[2] = (short)f2bf(lo.z); f[3] = (short)f2bf(lo.w);
        f[4] = (short)f2bf(hi.x); f[5] = (short)f2bf(hi.y);
        f[6] = (short)f2bf(hi.z); f[7] = (short)f2bf(hi.w);
        afr[kc] = f;
    }

    for (int t = 0; t < NT; t++) {
        f32x4 acc = {0.f, 0.f, 0.f, 0.f};
        // B[k][n]: n = t*16 + (lane&15), k = kc*32 + quad*8 + j  -> contiguous 16B in Wt
        const u16* bp = Wt + (size_t)(t * 16 + mrow) * K + quad * 8;
#pragma unroll
        for (int kc = 0; kc < KC; kc++) {
            s16x8 bfr = *reinterpret_cast<const s16x8*>(bp + kc * 32);
            acc = __builtin_amdgcn_mfma_f32_16x16x32_bf16(afr[kc], bfr, acc, 0, 0, 0);
        }
        // C/D: col = t*16 + (lane&15), row = m0 + quad*4 + r
#pragma unroll
        for (int r = 0; r < 4; r++) {
            int orow = m0 + quad * 4 + r;
            if (orow < M) {
                float v = acc[r];
                if (RELU_BIAS) v = fmaxf(v + bias[t * 16 + mrow], 0.f);
                if (OUT_BF16)
                    ((u16*)outp)[(size_t)orow * N + t * 16 + mrow] = f2bf(v);
                else
                    ((float*)outp)[(size_t)orow * N + t * 16 + mrow] = v;
            }
        }
    }
}

// ---- batchnorm stats (col sums + sumsq into stats[0..127],[128..255]) ----
__global__ void col_stats(const float* __restrict__ X, int M, float* __restrict__ stats) {
    int col = threadIdx.x;  // 128
    float s = 0.f, s2 = 0.f;
    for (int r = blockIdx.x; r < M; r += gridDim.x) {
        float v = X[(size_t)r * 128 + col];
        s += v; s2 += v * v;
    }
    atomicAdd(&stats[col], s);
    atomicAdd(&stats[128 + col], s2);
}

__global__ void bn_apply(float* __restrict__ X, const float* __restrict__ stats,
                         const float* __restrict__ gamma, const float* __restrict__ beta, int M) {
    int i = blockIdx.x * 256 + threadIdx.x;
    if (i >= M * 128) return;
    int col = i & 127;
    float inv_m = 1.0f / (float)M;
    float mu = stats[col] * inv_m;
    float var = stats[128 + col] * inv_m - mu * mu;
    float g = gamma[col], b = beta[col];
    X[i] = g * (X[i] - mu) * rsqrtf(var + BN_EPS) + b;
}

// ---- weff[h*128+k] = sum_c Wd[k, h*128+c] * ad[h*128+c] ----
__global__ void weff_kernel(const float* __restrict__ Wd, const float* __restrict__ ad,
                            float* __restrict__ weff) {
    int t = blockIdx.x * 256 + threadIdx.x;
    if (t >= 512) return;
    int h = t >> 7, k = t & 127;
    float s = 0.f;
    for (int c = 0; c < 128; c++)
        s += Wd[k * 512 + h * 128 + c] * ad[h * 128 + c];
    weff[h * 128 + k] = s;
}

// ---- ld[n,h] = X[n,:] @ weff[h,:]  (one wave per node) ----
__global__ void ld_kernel(const float* __restrict__ X, const float* __restrict__ weff,
                          float* __restrict__ ld, int M) {
    int wid = (blockIdx.x * blockDim.x + threadIdx.x) >> 6;
    int lane = threadIdx.x & 63;
    if (wid >= M) return;
    float x0 = X[(size_t)wid * 128 + lane];
    float x1 = X[(size_t)wid * 128 + 64 + lane];
    #pragma unroll
    for (int h = 0; h < 4; h++) {
        float p = x0 * weff[h * 128 + lane] + x1 * weff[h * 128 + 64 + lane];
        p += __shfl_xor(p, 32, 64);
        p += __shfl_xor(p, 16, 64);
        p += __shfl_xor(p, 8, 64);
        p += __shfl_xor(p, 4, 64);
        p += __shfl_xor(p, 2, 64);
        p += __shfl_xor(p, 1, 64);
        if (lane == 0) ld[wid * 4 + h] = p;
    }
}

// ---- ls[n,h] = sum_c xs[n,h,c]*as[h,c]  (one wave per node; xs bf16) ----
__global__ void ls_kernel(const u16* __restrict__ xs, const float* __restrict__ as_,
                          float* __restrict__ ls, int M) {
    int wid = (blockIdx.x * blockDim.x + threadIdx.x) >> 6;
    int lane = threadIdx.x & 63;
    if (wid >= M) return;
    float xv[8];
    load_bf16x8(xs + (size_t)wid * 512 + lane * 8, xv);
    const float* ap = as_ + lane * 8;
    float s = 0.f;
    #pragma unroll
    for (int k = 0; k < 8; k++) s += xv[k] * ap[k];
    s += __shfl_xor(s, 1, 64);
    s += __shfl_xor(s, 2, 64);
    s += __shfl_xor(s, 4, 64);
    s += __shfl_xor(s, 8, 64);
    if ((lane & 15) == 0) ls[wid * 4 + (lane >> 4)] = s;
}

// ---------------- CSR build ----------------
__global__ void count_edges(const int* __restrict__ src, const int* __restrict__ dst,
                            int E, int n_loop, int* __restrict__ deg) {
    int e = blockIdx.x * 256 + threadIdx.x;
    if (e >= E + n_loop) return;
    int s, d;
    if (e < E) { s = src[e]; d = dst[e]; if (s == d) return; }
    else { s = e - E; d = s; }
    atomicAdd(&deg[d], 1);
}

__global__ void scan_kernel(const int* __restrict__ deg, int* __restrict__ offs,
                            int* __restrict__ cursor, int n) {
    __shared__ int sums[1024];
    int tid = threadIdx.x;
    int per = (n + 1023) / 1024;
    int start = tid * per;
    int local = 0;
    for (int i = 0; i < per; i++) {
        int idx = start + i;
        if (idx < n) local += deg[idx];
    }
    sums[tid] = local;
    __syncthreads();
    for (int off = 1; off < 1024; off <<= 1) {
        int v = (tid >= off) ? sums[tid - off] : 0;
        __syncthreads();
        sums[tid] += v;
        __syncthreads();
    }
    int run = (tid == 0) ? 0 : sums[tid - 1];
    for (int i = 0; i < per; i++) {
        int idx = start + i;
        if (idx < n) { offs[idx] = run; cursor[idx] = run; run += deg[idx]; }
    }
    if (tid == 1023) offs[n] = sums[1023];
}

__global__ void scatter_edges(const int* __restrict__ src, const int* __restrict__ dst,
                              int E, int n_loop, int* __restrict__ cursor,
                              int* __restrict__ esrc) {
    int e = blockIdx.x * 256 + threadIdx.x;
    if (e >= E + n_loop) return;
    int s, d;
    if (e < E) { s = src[e]; d = dst[e]; if (s == d) return; }
    else { s = e - E; d = s; }
    int pos = atomicAdd(&cursor[d], 1);
    esrc[pos] = s;
}

// ---- GAT aggregation: one wave per dst node; updates xdst_out in place ----
__global__ void gat_kernel(const int* __restrict__ offs, const int* __restrict__ esrc,
                           const float* __restrict__ ls, const float* __restrict__ ld,
                           const u16* __restrict__ xs, const float* __restrict__ bias,
                           float* __restrict__ xdst_out, int n_dst) {
    int wid = (blockIdx.x * blockDim.x + threadIdx.x) >> 6;
    int lane = threadIdx.x & 63;
    if (wid >= n_dst) return;
    int h = lane >> 4;
    int beg = offs[wid], end = offs[wid + 1];
    float ldv = ld[wid * 4 + h];
    float m = -INFINITY;
    for (int j = beg; j < end; j++) {
        int s = esrc[j];
        float l = ls[s * 4 + h] + ldv;
        l = l > 0.f ? l : 0.2f * l;
        m = fmaxf(m, l);
    }
    float denom = 0.f;
    float acc[8] = {0.f, 0.f, 0.f, 0.f, 0.f, 0.f, 0.f, 0.f};
    for (int j = beg; j < end; j++) {
        int s = esrc[j];
        float l = ls[s * 4 + h] + ldv;
        l = l > 0.f ? l : 0.2f * l;
        float p = __expf(l - m);
        denom += p;
        float xv[8];
        load_bf16x8(xs + (size_t)s * 512 + lane * 8, xv);
        #pragma unroll
        for (int k = 0; k < 8; k++) acc[k] += p * xv[k];
    }
    float dinv = denom > 0.f ? 1.f / denom : 1.f;
    #pragma unroll
    for (int k = 0; k < 8; k++) {
        float v = acc[k] * dinv;
        v += __shfl_xor(v, 16, 64);
        v += __shfl_xor(v, 32, 64);
        acc[k] = v * 0.25f;
    }
    if (lane < 16) {
        int c0 = lane * 8;
        #pragma unroll
        for (int k = 0; k < 8; k++) {
            xdst_out[(size_t)wid * 128 + c0 + k] += acc[k] + bias[c0 + k];
        }
    }
}

static inline int cdiv(int a, int b) { return (a + b - 1) / b; }

extern "C" void kernel_launch(void* const* d_in, const int* in_sizes, int n_in,
                              void* d_out, int out_size, void* d_ws, size_t ws_size,
                              hipStream_t stream) {
    const float* x_gene = (const float*)d_in[0];
    const float* x_dis  = (const float*)d_in[1];
    const int* e1s = (const int*)d_in[2];
    const int* e1d = (const int*)d_in[3];
    const int* e2s = (const int*)d_in[4];
    const int* e2d = (const int*)d_in[5];
    const float *Wg = (const float*)d_in[6],  *bg = (const float*)d_in[7];
    const float *gg = (const float*)d_in[8],  *betag = (const float*)d_in[9];
    const float *Wd = (const float*)d_in[10], *bd = (const float*)d_in[11];
    const float *gd = (const float*)d_in[12], *betad = (const float*)d_in[13];
    const float *W1s = (const float*)d_in[14], *W1d = (const float*)d_in[15];
    const float *a1s = (const float*)d_in[16], *a1d = (const float*)d_in[17];
    const float *b1  = (const float*)d_in[18];
    const float *W2s = (const float*)d_in[19], *W2d = (const float*)d_in[20];
    const float *a2s = (const float*)d_in[21], *a2d = (const float*)d_in[22];
    const float *b2  = (const float*)d_in[23];

    // outputs live directly in d_out (fully overwritten by encode, then updated in place)
    float* gene_f = (float*)d_out;                      // [N_GENE,128]
    float* dis_f  = (float*)d_out + (size_t)N_GENE * 128;  // [N_DIS,128]

    // workspace layout (all 256B aligned)
    char* p = (char*)d_ws;
    auto alloc = [&](size_t bytes) {
        char* r = p;
        p += (bytes + 255) & ~(size_t)255;
        return r;
    };
    u16*   xs_buf = (u16*)  alloc((size_t)N_GENE * 512 * 2);
    float* ls_buf = (float*)alloc((size_t)N_GENE * 4 * 4);
    float* ld_buf = (float*)alloc((size_t)N_GENE * 4 * 4);
    float* weff   = (float*)alloc(512 * 4);
    float* stats  = (float*)alloc(256 * 4);
    int*   deg    = (int*)  alloc((size_t)N_GENE * 4);
    int*   offs   = (int*)  alloc((size_t)(N_GENE + 1) * 4);
    int*   cursor = (int*)  alloc((size_t)N_GENE * 4);
    int*   esrc   = (int*)  alloc((size_t)(E_EDGES + N_GENE) * 4);
    u16*   Wgt  = (u16*)alloc((size_t)512 * 128 * 2);  // [128][512] bf16
    u16*   Wdt  = (u16*)alloc((size_t)256 * 128 * 2);  // [128][256]
    u16*   W1st = (u16*)alloc((size_t)128 * 512 * 2);  // [512][128]
    u16*   W2st = (u16*)alloc((size_t)128 * 512 * 2);  // [512][128]

    // ---- weight pre-transpose to bf16 [n][k] ----
    wtrans_kernel<<<256, 256, 0, stream>>>(Wg,  Wgt,  512, 128);
    wtrans_kernel<<<128, 256, 0, stream>>>(Wd,  Wdt,  256, 128);
    wtrans_kernel<<<256, 256, 0, stream>>>(W1s, W1st, 128, 512);
    wtrans_kernel<<<256, 256, 0, stream>>>(W2s, W2st, 128, 512);

    // ---- encode gene: relu(x_gene @ Wg + bg) -> BN ----
    zero_kernel<<<1, 256, 0, stream>>>((int*)stats, 256);
    mfma_gemm<512, 128, true, false><<<cdiv(N_GENE, 64), 256, 0, stream>>>(x_gene, Wgt, bg, gene_f, N_GENE);
    col_stats<<<512, 128, 0, stream>>>(gene_f, N_GENE, stats);
    bn_apply<<<cdiv(N_GENE * 128, 256), 256, 0, stream>>>(gene_f, stats, gg, betag, N_GENE);

    // ---- encode dis ----
    zero_kernel<<<1, 256, 0, stream>>>((int*)stats, 256);
    mfma_gemm<256, 128, true, false><<<cdiv(N_DIS, 64), 256, 0, stream>>>(x_dis, Wdt, bd, dis_f, N_DIS);
    col_stats<<<512, 128, 0, stream>>>(dis_f, N_DIS, stats);
    bn_apply<<<cdiv(N_DIS * 128, 256), 256, 0, stream>>>(dis_f, stats, gd, betad, N_DIS);

    // ---- relation 1: Disease -> Gene ----
    mfma_gemm<128, 512, false, true><<<cdiv(N_DIS, 64), 256, 0, stream>>>(dis_f, W1st, nullptr, xs_buf, N_DIS);
    ls_kernel<<<cdiv(N_DIS, 4), 256, 0, stream>>>(xs_buf, a1s, ls_buf, N_DIS);
    weff_kernel<<<2, 256, 0, stream>>>(W1d, a1d, weff);
    ld_kernel<<<cdiv(N_GENE, 4), 256, 0, stream>>>(gene_f, weff, ld_buf, N_GENE);
    zero_kernel<<<cdiv(N_GENE, 256), 256, 0, stream>>>(deg, N_GENE);
    count_edges<<<cdiv(E_EDGES + N_DIS, 256), 256, 0, stream>>>(e1s, e1d, E_EDGES, N_DIS, deg);
    scan_kernel<<<1, 1024, 0, stream>>>(deg, offs, cursor, N_GENE);
    scatter_edges<<<cdiv(E_EDGES + N_DIS, 256), 256, 0, stream>>>(e1s, e1d, E_EDGES, N_DIS, cursor, esrc);
    gat_kernel<<<cdiv(N_GENE, 4), 256, 0, stream>>>(offs, esrc, ls_buf, ld_buf, xs_buf, b1, gene_f, N_GENE);

    // ---- relation 2: Gene -> Gene (updated gene) ----
    mfma_gemm<128, 512, false, true><<<cdiv(N_GENE, 64), 256, 0, stream>>>(gene_f, W2st, nullptr, xs_buf, N_GENE);
    ls_kernel<<<cdiv(N_GENE, 4), 256, 0, stream>>>(xs_buf, a2s, ls_buf, N_GENE);
    weff_kernel<<<2, 256, 0, stream>>>(W2d, a2d, weff);
    ld_kernel<<<cdiv(N_GENE, 4), 256, 0, stream>>>(gene_f, weff, ld_buf, N_GENE);
    zero_kernel<<<cdiv(N_GENE, 256), 256, 0, stream>>>(deg, N_GENE);
    count_edges<<<cdiv(E_EDGES + N_GENE, 256), 256, 0, stream>>>(e2s, e2d, E_EDGES, N_GENE, deg);
    scan_kernel<<<1, 1024, 0, stream>>>(deg, offs, cursor, N_GENE);
    scatter_edges<<<cdiv(E_EDGES + N_GENE, 256), 256, 0, stream>>>(e2s, e2d, E_EDGES, N_GENE, cursor, esrc);
    gat_kernel<<<cdiv(N_GENE, 4), 256, 0, stream>>>(offs, esrc, ls_buf, ld_buf, xs_buf, b2, gene_f, N_GENE);
}

// Round 4
// 722.953 us; speedup vs baseline: 1.7782x; 1.3252x over previous
//
#include <hip/hip_runtime.h>
#include <hip/hip_bf16.h>
#include <math.h>

#define N_GENE 50000
#define N_DIS  25000
#define F_GENE 512
#define F_DIS  256
#define E_EDGES 150000
#define BN_EPS 1e-5f

typedef unsigned short u16;
typedef short s16x8 __attribute__((ext_vector_type(8)));
typedef float f32x4 __attribute__((ext_vector_type(4)));

__device__ __forceinline__ u16 f2bf(float f) {
    union { float f; unsigned u; } c; c.f = f;
    unsigned u = c.u;
    unsigned rounding = 0x7FFFu + ((u >> 16) & 1u);
    return (u16)((u + rounding) >> 16);
}
__device__ __forceinline__ void load_bf16x8(const u16* p, float* f) {
    uint4 q = *reinterpret_cast<const uint4*>(p);
    unsigned w0 = q.x, w1 = q.y, w2 = q.z, w3 = q.w;
    f[0] = __uint_as_float(w0 << 16); f[1] = __uint_as_float(w0 & 0xffff0000u);
    f[2] = __uint_as_float(w1 << 16); f[3] = __uint_as_float(w1 & 0xffff0000u);
    f[4] = __uint_as_float(w2 << 16); f[5] = __uint_as_float(w2 & 0xffff0000u);
    f[6] = __uint_as_float(w3 << 16); f[7] = __uint_as_float(w3 & 0xffff0000u);
}

// ---------------- zero fill ----------------
__global__ void zero_kernel(int* p, int n) {
    int i = blockIdx.x * 256 + threadIdx.x;
    if (i < n) p[i] = 0;
}

// ---- W pre-transpose: wt[n*K+k] = bf16(W[k*N+n]) ----
__global__ void wtrans_kernel(const float* __restrict__ W, u16* __restrict__ wt, int K, int N) {
    int i = blockIdx.x * 256 + threadIdx.x;
    if (i >= K * N) return;
    int k = i / N, n = i - k * N;
    wt[n * K + k] = f2bf(W[i]);
}

// ---- MFMA GEMM: out[M,N] = op(A[M,K]f32 @ Wt^T) ; Wt is [N,K] bf16 ----
template <int K, int N, bool RELU_BIAS, bool OUT_BF16>
__global__ __launch_bounds__(256) void mfma_gemm(const float* __restrict__ A,
                                                 const u16* __restrict__ Wt,
                                                 const float* __restrict__ bias,
                                                 void* __restrict__ outp, int M) {
    constexpr int KC = K / 32;   // k-chunks of 32
    constexpr int NT = N / 16;   // n-tiles of 16
    int wave = threadIdx.x >> 6;
    int lane = threadIdx.x & 63;
    int m0 = (blockIdx.x * 4 + wave) * 16;
    if (m0 >= M) return;                 // wave-uniform
    int mrow = lane & 15;
    int quad = lane >> 4;
    int row = m0 + mrow;
    int arow = row < M ? row : M - 1;    // clamp OOB loads; stores guarded below

    s16x8 afr[KC];
#pragma unroll
    for (int kc = 0; kc < KC; kc++) {
        const float* ap = A + (size_t)arow * K + kc * 32 + quad * 8;
        float4 lo = *reinterpret_cast<const float4*>(ap);
        float4 hi = *reinterpret_cast<const float4*>(ap + 4);
        s16x8 f;
        f[0] = (short)f2bf(lo.x); f[1] = (short)f2bf(lo.y);
        f[2] = (short)f2bf(lo.z); f[3] = (short)f2bf(lo.w);
        f[4] = (short)f2bf(hi.x); f[5] = (short)f2bf(hi.y);
        f[6] = (short)f2bf(hi.z); f[7] = (short)f2bf(hi.w);
        afr[kc] = f;
    }

    for (int t = 0; t < NT; t++) {
        f32x4 acc = {0.f, 0.f, 0.f, 0.f};
        const u16* bp = Wt + (size_t)(t * 16 + mrow) * K + quad * 8;
#pragma unroll
        for (int kc = 0; kc < KC; kc++) {
            s16x8 bfr = *reinterpret_cast<const s16x8*>(bp + kc * 32);
            acc = __builtin_amdgcn_mfma_f32_16x16x32_bf16(afr[kc], bfr, acc, 0, 0, 0);
        }
#pragma unroll
        for (int r = 0; r < 4; r++) {
            int orow = m0 + quad * 4 + r;
            if (orow < M) {
                float v = acc[r];
                if (RELU_BIAS) v = fmaxf(v + bias[t * 16 + mrow], 0.f);
                if (OUT_BF16)
                    ((u16*)outp)[(size_t)orow * N + t * 16 + mrow] = f2bf(v);
                else
                    ((float*)outp)[(size_t)orow * N + t * 16 + mrow] = v;
            }
        }
    }
}

// ---- batchnorm stats ----
__global__ void col_stats(const float* __restrict__ X, int M, float* __restrict__ stats) {
    int col = threadIdx.x;  // 128
    float s = 0.f, s2 = 0.f;
    for (int r = blockIdx.x; r < M; r += gridDim.x) {
        float v = X[(size_t)r * 128 + col];
        s += v; s2 += v * v;
    }
    atomicAdd(&stats[col], s);
    atomicAdd(&stats[128 + col], s2);
}

__global__ void bn_apply(float* __restrict__ X, const float* __restrict__ stats,
                         const float* __restrict__ gamma, const float* __restrict__ beta, int M) {
    int i = blockIdx.x * 256 + threadIdx.x;
    if (i >= M * 128) return;
    int col = i & 127;
    float inv_m = 1.0f / (float)M;
    float mu = stats[col] * inv_m;
    float var = stats[128 + col] * inv_m - mu * mu;
    float g = gamma[col], b = beta[col];
    X[i] = g * (X[i] - mu) * rsqrtf(var + BN_EPS) + b;
}

// ---- weff[h*128+k] = sum_c Wd[k, h*128+c] * ad[h*128+c] ----
__global__ void weff_kernel(const float* __restrict__ Wd, const float* __restrict__ ad,
                            float* __restrict__ weff) {
    int t = blockIdx.x * 256 + threadIdx.x;
    if (t >= 512) return;
    int h = t >> 7, k = t & 127;
    float s = 0.f;
    for (int c = 0; c < 128; c++)
        s += Wd[k * 512 + h * 128 + c] * ad[h * 128 + c];
    weff[h * 128 + k] = s;
}

// ---- ld[n,h] = X[n,:] @ weff[h,:]  (one wave per node) ----
__global__ void ld_kernel(const float* __restrict__ X, const float* __restrict__ weff,
                          float* __restrict__ ld, int M) {
    int wid = (blockIdx.x * blockDim.x + threadIdx.x) >> 6;
    int lane = threadIdx.x & 63;
    if (wid >= M) return;
    float x0 = X[(size_t)wid * 128 + lane];
    float x1 = X[(size_t)wid * 128 + 64 + lane];
    #pragma unroll
    for (int h = 0; h < 4; h++) {
        float p = x0 * weff[h * 128 + lane] + x1 * weff[h * 128 + 64 + lane];
        p += __shfl_xor(p, 32, 64);
        p += __shfl_xor(p, 16, 64);
        p += __shfl_xor(p, 8, 64);
        p += __shfl_xor(p, 4, 64);
        p += __shfl_xor(p, 2, 64);
        p += __shfl_xor(p, 1, 64);
        if (lane == 0) ld[wid * 4 + h] = p;
    }
}

// ---- ls[n,h] = sum_c xs[n,h,c]*as[h,c] ----
__global__ void ls_kernel(const u16* __restrict__ xs, const float* __restrict__ as_,
                          float* __restrict__ ls, int M) {
    int wid = (blockIdx.x * blockDim.x + threadIdx.x) >> 6;
    int lane = threadIdx.x & 63;
    if (wid >= M) return;
    float xv[8];
    load_bf16x8(xs + (size_t)wid * 512 + lane * 8, xv);
    const float* ap = as_ + lane * 8;
    float s = 0.f;
    #pragma unroll
    for (int k = 0; k < 8; k++) s += xv[k] * ap[k];
    s += __shfl_xor(s, 1, 64);
    s += __shfl_xor(s, 2, 64);
    s += __shfl_xor(s, 4, 64);
    s += __shfl_xor(s, 8, 64);
    if ((lane & 15) == 0) ls[wid * 4 + (lane >> 4)] = s;
}

// ---------------- CSR build ----------------
__global__ void count_edges(const int* __restrict__ src, const int* __restrict__ dst,
                            int E, int n_loop, int* __restrict__ deg) {
    int e = blockIdx.x * 256 + threadIdx.x;
    if (e >= E + n_loop) return;
    int s, d;
    if (e < E) { s = src[e]; d = dst[e]; if (s == d) return; }
    else { s = e - E; d = s; }
    atomicAdd(&deg[d], 1);
}

// two-level parallel exclusive scan: block_sum -> scan_bsum -> scan_final
__global__ void block_sum(const int* __restrict__ deg, int* __restrict__ bsum, int n) {
    __shared__ int sh[256];
    int i = blockIdx.x * 256 + threadIdx.x;
    sh[threadIdx.x] = (i < n) ? deg[i] : 0;
    __syncthreads();
    for (int s = 128; s > 0; s >>= 1) {
        if (threadIdx.x < s) sh[threadIdx.x] += sh[threadIdx.x + s];
        __syncthreads();
    }
    if (threadIdx.x == 0) bsum[blockIdx.x] = sh[0];
}

__global__ void scan_bsum(int* __restrict__ bsum, int nb, int* __restrict__ total_out) {
    __shared__ int sh[256];
    int tid = threadIdx.x;
    int v = (tid < nb) ? bsum[tid] : 0;
    sh[tid] = v;
    __syncthreads();
    for (int off = 1; off < 256; off <<= 1) {
        int t = (tid >= off) ? sh[tid - off] : 0;
        __syncthreads();
        sh[tid] += t;
        __syncthreads();
    }
    if (tid < nb) bsum[tid] = sh[tid] - v;   // exclusive
    if (tid == 255) *total_out = sh[255];
}

__global__ void scan_final(const int* __restrict__ deg, const int* __restrict__ bsum,
                           int* __restrict__ offs, int* __restrict__ cursor, int n) {
    __shared__ int sh[256];
    int i = blockIdx.x * 256 + threadIdx.x;
    int tid = threadIdx.x;
    int v = (i < n) ? deg[i] : 0;
    sh[tid] = v;
    __syncthreads();
    for (int off = 1; off < 256; off <<= 1) {
        int t = (tid >= off) ? sh[tid - off] : 0;
        __syncthreads();
        sh[tid] += t;
        __syncthreads();
    }
    int ex = bsum[blockIdx.x] + sh[tid] - v;
    if (i < n) { offs[i] = ex; cursor[i] = ex; }
}

__global__ void scatter_edges(const int* __restrict__ src, const int* __restrict__ dst,
                              int E, int n_loop, int* __restrict__ cursor,
                              int* __restrict__ esrc) {
    int e = blockIdx.x * 256 + threadIdx.x;
    if (e >= E + n_loop) return;
    int s, d;
    if (e < E) { s = src[e]; d = dst[e]; if (s == d) return; }
    else { s = e - E; d = s; }
    int pos = atomicAdd(&cursor[d], 1);
    esrc[pos] = s;
}

// ---- GAT aggregation: one wave per dst node; updates xdst_out in place ----
__global__ void gat_kernel(const int* __restrict__ offs, const int* __restrict__ esrc,
                           const float* __restrict__ ls, const float* __restrict__ ld,
                           const u16* __restrict__ xs, const float* __restrict__ bias,
                           float* __restrict__ xdst_out, int n_dst) {
    int wid = (blockIdx.x * blockDim.x + threadIdx.x) >> 6;
    int lane = threadIdx.x & 63;
    if (wid >= n_dst) return;
    int h = lane >> 4;
    int beg = offs[wid], end = offs[wid + 1];
    float ldv = ld[wid * 4 + h];
    float m = -INFINITY;
    for (int j = beg; j < end; j++) {
        int s = esrc[j];
        float l = ls[s * 4 + h] + ldv;
        l = l > 0.f ? l : 0.2f * l;
        m = fmaxf(m, l);
    }
    float denom = 0.f;
    float acc[8] = {0.f, 0.f, 0.f, 0.f, 0.f, 0.f, 0.f, 0.f};
    for (int j = beg; j < end; j++) {
        int s = esrc[j];
        float l = ls[s * 4 + h] + ldv;
        l = l > 0.f ? l : 0.2f * l;
        float p = __expf(l - m);
        denom += p;
        float xv[8];
        load_bf16x8(xs + (size_t)s * 512 + lane * 8, xv);
        #pragma unroll
        for (int k = 0; k < 8; k++) acc[k] += p * xv[k];
    }
    float dinv = denom > 0.f ? 1.f / denom : 1.f;
    #pragma unroll
    for (int k = 0; k < 8; k++) {
        float v = acc[k] * dinv;
        v += __shfl_xor(v, 16, 64);
        v += __shfl_xor(v, 32, 64);
        acc[k] = v * 0.25f;
    }
    if (lane < 16) {
        int c0 = lane * 8;
        #pragma unroll
        for (int k = 0; k < 8; k++) {
            xdst_out[(size_t)wid * 128 + c0 + k] += acc[k] + bias[c0 + k];
        }
    }
}

static inline int cdiv(int a, int b) { return (a + b - 1) / b; }

extern "C" void kernel_launch(void* const* d_in, const int* in_sizes, int n_in,
                              void* d_out, int out_size, void* d_ws, size_t ws_size,
                              hipStream_t stream) {
    const float* x_gene = (const float*)d_in[0];
    const float* x_dis  = (const float*)d_in[1];
    const int* e1s = (const int*)d_in[2];
    const int* e1d = (const int*)d_in[3];
    const int* e2s = (const int*)d_in[4];
    const int* e2d = (const int*)d_in[5];
    const float *Wg = (const float*)d_in[6],  *bg = (const float*)d_in[7];
    const float *gg = (const float*)d_in[8],  *betag = (const float*)d_in[9];
    const float *Wd = (const float*)d_in[10], *bd = (const float*)d_in[11];
    const float *gd = (const float*)d_in[12], *betad = (const float*)d_in[13];
    const float *W1s = (const float*)d_in[14], *W1d = (const float*)d_in[15];
    const float *a1s = (const float*)d_in[16], *a1d = (const float*)d_in[17];
    const float *b1  = (const float*)d_in[18];
    const float *W2s = (const float*)d_in[19], *W2d = (const float*)d_in[20];
    const float *a2s = (const float*)d_in[21], *a2d = (const float*)d_in[22];
    const float *b2  = (const float*)d_in[23];

    float* gene_f = (float*)d_out;                         // [N_GENE,128]
    float* dis_f  = (float*)d_out + (size_t)N_GENE * 128;  // [N_DIS,128]

    char* p = (char*)d_ws;
    auto alloc = [&](size_t bytes) {
        char* r = p;
        p += (bytes + 255) & ~(size_t)255;
        return r;
    };
    u16*   xs_buf = (u16*)  alloc((size_t)N_GENE * 512 * 2);
    float* ls_buf = (float*)alloc((size_t)N_GENE * 4 * 4);
    float* ld_buf = (float*)alloc((size_t)N_GENE * 4 * 4);
    float* weff   = (float*)alloc(512 * 4);
    float* stats  = (float*)alloc(256 * 4);
    int*   deg    = (int*)  alloc((size_t)N_GENE * 4);
    int*   offs   = (int*)  alloc((size_t)(N_GENE + 1) * 4);
    int*   cursor = (int*)  alloc((size_t)N_GENE * 4);
    int*   bsum   = (int*)  alloc(256 * 4);
    int*   esrc   = (int*)  alloc((size_t)(E_EDGES + N_GENE) * 4);
    u16*   Wgt  = (u16*)alloc((size_t)512 * 128 * 2);
    u16*   Wdt  = (u16*)alloc((size_t)256 * 128 * 2);
    u16*   W1st = (u16*)alloc((size_t)128 * 512 * 2);
    u16*   W2st = (u16*)alloc((size_t)128 * 512 * 2);

    const int NB = cdiv(N_GENE, 256);  // 196

    // ---- weight pre-transpose to bf16 [n][k] ----
    wtrans_kernel<<<256, 256, 0, stream>>>(Wg,  Wgt,  512, 128);
    wtrans_kernel<<<128, 256, 0, stream>>>(Wd,  Wdt,  256, 128);
    wtrans_kernel<<<256, 256, 0, stream>>>(W1s, W1st, 128, 512);
    wtrans_kernel<<<256, 256, 0, stream>>>(W2s, W2st, 128, 512);

    // ---- encode gene ----
    zero_kernel<<<1, 256, 0, stream>>>((int*)stats, 256);
    mfma_gemm<512, 128, true, false><<<cdiv(N_GENE, 64), 256, 0, stream>>>(x_gene, Wgt, bg, gene_f, N_GENE);
    col_stats<<<512, 128, 0, stream>>>(gene_f, N_GENE, stats);
    bn_apply<<<cdiv(N_GENE * 128, 256), 256, 0, stream>>>(gene_f, stats, gg, betag, N_GENE);

    // ---- encode dis ----
    zero_kernel<<<1, 256, 0, stream>>>((int*)stats, 256);
    mfma_gemm<256, 128, true, false><<<cdiv(N_DIS, 64), 256, 0, stream>>>(x_dis, Wdt, bd, dis_f, N_DIS);
    col_stats<<<512, 128, 0, stream>>>(dis_f, N_DIS, stats);
    bn_apply<<<cdiv(N_DIS * 128, 256), 256, 0, stream>>>(dis_f, stats, gd, betad, N_DIS);

    // ---- relation 1: Disease -> Gene ----
    mfma_gemm<128, 512, false, true><<<cdiv(N_DIS, 64), 256, 0, stream>>>(dis_f, W1st, nullptr, xs_buf, N_DIS);
    ls_kernel<<<cdiv(N_DIS, 4), 256, 0, stream>>>(xs_buf, a1s, ls_buf, N_DIS);
    weff_kernel<<<2, 256, 0, stream>>>(W1d, a1d, weff);
    ld_kernel<<<cdiv(N_GENE, 4), 256, 0, stream>>>(gene_f, weff, ld_buf, N_GENE);
    zero_kernel<<<cdiv(N_GENE, 256), 256, 0, stream>>>(deg, N_GENE);
    count_edges<<<cdiv(E_EDGES + N_DIS, 256), 256, 0, stream>>>(e1s, e1d, E_EDGES, N_DIS, deg);
    block_sum<<<NB, 256, 0, stream>>>(deg, bsum, N_GENE);
    scan_bsum<<<1, 256, 0, stream>>>(bsum, NB, &offs[N_GENE]);
    scan_final<<<NB, 256, 0, stream>>>(deg, bsum, offs, cursor, N_GENE);
    scatter_edges<<<cdiv(E_EDGES + N_DIS, 256), 256, 0, stream>>>(e1s, e1d, E_EDGES, N_DIS, cursor, esrc);
    gat_kernel<<<cdiv(N_GENE, 4), 256, 0, stream>>>(offs, esrc, ls_buf, ld_buf, xs_buf, b1, gene_f, N_GENE);

    // ---- relation 2: Gene -> Gene ----
    mfma_gemm<128, 512, false, true><<<cdiv(N_GENE, 64), 256, 0, stream>>>(gene_f, W2st, nullptr, xs_buf, N_GENE);
    ls_kernel<<<cdiv(N_GENE, 4), 256, 0, stream>>>(xs_buf, a2s, ls_buf, N_GENE);
    weff_kernel<<<2, 256, 0, stream>>>(W2d, a2d, weff);
    ld_kernel<<<cdiv(N_GENE, 4), 256, 0, stream>>>(gene_f, weff, ld_buf, N_GENE);
    zero_kernel<<<cdiv(N_GENE, 256), 256, 0, stream>>>(deg, N_GENE);
    count_edges<<<cdiv(E_EDGES + N_GENE, 256), 256, 0, stream>>>(e2s, e2d, E_EDGES, N_GENE, deg);
    block_sum<<<NB, 256, 0, stream>>>(deg, bsum, N_GENE);
    scan_bsum<<<1, 256, 0, stream>>>(bsum, NB, &offs[N_GENE]);
    scan_final<<<NB, 256, 0, stream>>>(deg, bsum, offs, cursor, N_GENE);
    scatter_edges<<<cdiv(E_EDGES + N_GENE, 256), 256, 0, stream>>>(e2s, e2d, E_EDGES, N_GENE, cursor, esrc);
    gat_kernel<<<cdiv(N_GENE, 4), 256, 0, stream>>>(offs, esrc, ls_buf, ld_buf, xs_buf, b2, gene_f, N_GENE);
}